// Round 8
// baseline (1046.662 us; speedup 1.0000x reference)
//
#include <hip/hip_runtime.h>

// ---------------------------------------------------------------------------
// Double attention, round 8 = round-7 source resubmitted verbatim (round 7
// bench was a GPUAcquisitionTimeout; no signal). f32.
//   B=64 S=32 N=64 E=128 H=4 D=32
// vs round 6 (589 us total; main 247 us VALUBusy 45% Occ 38%):
//  * main: wave-per-n mapping (8 waves = 8 n per 512-thr block) -> adjacency
//    skip is WAVE-uniform: ~50% of (n,m) pairs skip scores/softmax/PV/sc2
//    entirely (exact math: masked pairs are online-update no-ops).
//    LDS 55->43.5 KB -> 3 blocks/CU; launch_bounds(512,6).
//  * ktvt: W staged in 16-k chunks -> LDS 67.5->50.6 KB -> 3 blocks/CU.
// ---------------------------------------------------------------------------

constexpr int Bb = 64, Ss = 32, Nn = 64, Ee = 128, Hh = 4, Dd = 32;
constexpr int MS = 2;                       // m-split factor
constexpr float SCALE = 0.17677669529663687f;  // 1/sqrt(32)

__device__ __forceinline__ float4 f4_load(const float* p) {
  return *reinterpret_cast<const float4*>(p);
}
__device__ __forceinline__ void f4_store(float* p, float4 v) {
  *reinterpret_cast<float4*>(p) = v;
}
__device__ __forceinline__ float dot4(float4 a, float4 b) {
  return a.x * b.x + a.y * b.y + a.z * b.z + a.w * b.w;
}

// ---------------- fold stage-2 K/V weights through t_Wo --------------------
__global__ __launch_bounds__(128) void fuse_weights_kernel(
    const float* __restrict__ sWk, const float* __restrict__ sbk,
    const float* __restrict__ sWv, const float* __restrict__ sbv,
    const float* __restrict__ tWo, const float* __restrict__ tbo,
    float* __restrict__ Wkp, float* __restrict__ bkp,
    float* __restrict__ Wvp, float* __restrict__ bvp) {
  const int i = blockIdx.x;
  const int which = blockIdx.y;
  const float* sW = which ? sWv : sWk;
  const float* sb = which ? sbv : sbk;
  float* Wp = which ? Wvp : Wkp;
  float* bp = which ? bvp : bkp;
  __shared__ float srow[Ee];
  const int t = threadIdx.x;
  srow[t] = sW[i * Ee + t];
  __syncthreads();
  float acc = 0.f;
  for (int k = 0; k < Ee; ++k) acc += srow[k] * tWo[k * Ee + t];
  Wp[i * Ee + t] = acc;
  if (t == 0) {
    float bb = sb[i];
    for (int k = 0; k < Ee; ++k) bb += srow[k] * tbo[k];
    bp[i] = bb;
  }
}

// ---------------- q projections + qk2/qb2 ----------------------------------
// grid (B, 2). which=0: qt = q@tWq^T+tbq -> qt_ws.
// which=1: qs = q@sWq^T+sbq (kept in LDS), then
//   qk2[n,h,e] = sum_d qs[n,hD+d]*Wk'[hD+d][e], qb2[n,h] = sum_d qs*bk'.
__global__ __launch_bounds__(256) void qproj_kernel(
    const float* __restrict__ x,
    const float* __restrict__ tWq, const float* __restrict__ tbq,
    const float* __restrict__ sWq, const float* __restrict__ sbq,
    const float* __restrict__ Wkp, const float* __restrict__ bkp,
    float* __restrict__ qt_ws, float* __restrict__ qk2_ws,
    float* __restrict__ qb2_ws) {
  __shared__ float q_l[64 * 132];   // [n][132]
  __shared__ float W_l[32 * 128];   // k-quarter, [k][e]
  __shared__ float bk_l[128];
  const int b = blockIdx.x;
  const int which = blockIdx.y;
  const float* W = which ? sWq : tWq;
  const float* bias = which ? sbq : tbq;
  const int t = threadIdx.x;
  // stage q rows (x[b, S-1, n, :])
  for (int idx = t; idx < 2048; idx += 256) {
    int nn = idx >> 5, e4 = (idx & 31) << 2;
    f4_store(&q_l[nn * 132 + e4],
             f4_load(&x[(((size_t)b * Ss + (Ss - 1)) * Nn + nn) * Ee + e4]));
  }
  if (which && t < 32) f4_store(&bk_l[t * 4], f4_load(&bkp[t * 4]));

  const int ng = t >> 5;
  const int e0 = (t & 31) << 2;
  float4 acc[8];
#pragma unroll
  for (int j = 0; j < 8; ++j) acc[j] = make_float4(0.f, 0.f, 0.f, 0.f);

  for (int kq = 0; kq < 4; ++kq) {
    __syncthreads();
    // stage W quarter transposed: W_l[k][e] from W[e][kq*32+k]
    for (int idx = t; idx < 1024; idx += 256) {
      int e = idx & 127, k0 = (idx >> 7) << 2;
      float4 w = f4_load(&W[e * Ee + kq * 32 + k0]);
      W_l[(k0 + 0) * 128 + e] = w.x;
      W_l[(k0 + 1) * 128 + e] = w.y;
      W_l[(k0 + 2) * 128 + e] = w.z;
      W_l[(k0 + 3) * 128 + e] = w.w;
    }
    __syncthreads();
#pragma unroll
    for (int j = 0; j < 8; ++j) {
      const int n = ng * 8 + j;
      float4 a = acc[j];
      for (int k0 = 0; k0 < 32; k0 += 4) {
        float4 qv = f4_load(&q_l[n * 132 + kq * 32 + k0]);
        float4 w0 = f4_load(&W_l[(k0 + 0) * 128 + e0]);
        float4 w1 = f4_load(&W_l[(k0 + 1) * 128 + e0]);
        float4 w2 = f4_load(&W_l[(k0 + 2) * 128 + e0]);
        float4 w3 = f4_load(&W_l[(k0 + 3) * 128 + e0]);
        a.x += qv.x * w0.x + qv.y * w1.x + qv.z * w2.x + qv.w * w3.x;
        a.y += qv.x * w0.y + qv.y * w1.y + qv.z * w2.y + qv.w * w3.y;
        a.z += qv.x * w0.z + qv.y * w1.z + qv.z * w2.z + qv.w * w3.z;
        a.w += qv.x * w0.w + qv.y * w1.w + qv.z * w2.w + qv.w * w3.w;
      }
      acc[j] = a;
    }
  }
  float4 bb = f4_load(&bias[e0]);
#pragma unroll
  for (int j = 0; j < 8; ++j) {
    acc[j].x += bb.x; acc[j].y += bb.y; acc[j].z += bb.z; acc[j].w += bb.w;
  }
  if (which == 0) {
#pragma unroll
    for (int j = 0; j < 8; ++j)
      f4_store(&qt_ws[((size_t)b * Nn + ng * 8 + j) * Ee + e0], acc[j]);
    return;
  }
  // ---- qs -> q_l, then qk2 / qb2 ----
  __syncthreads();
#pragma unroll
  for (int j = 0; j < 8; ++j)
    f4_store(&q_l[(ng * 8 + j) * 132 + e0], acc[j]);
  for (int h = 0; h < 4; ++h) {
    __syncthreads();
    for (int idx = t; idx < 1024; idx += 256) {  // stage Wk' rows (plain)
      int kk = idx >> 5, e4 = (idx & 31) << 2;
      f4_store(&W_l[kk * 128 + e4], f4_load(&Wkp[(h * 32 + kk) * Ee + e4]));
    }
    __syncthreads();
#pragma unroll
    for (int j = 0; j < 8; ++j) {
      const int n = ng * 8 + j;
      float4 a = make_float4(0.f, 0.f, 0.f, 0.f);
      for (int d0 = 0; d0 < 32; d0 += 4) {
        float4 qv = f4_load(&q_l[n * 132 + h * 32 + d0]);
        float4 w0 = f4_load(&W_l[(d0 + 0) * 128 + e0]);
        float4 w1 = f4_load(&W_l[(d0 + 1) * 128 + e0]);
        float4 w2 = f4_load(&W_l[(d0 + 2) * 128 + e0]);
        float4 w3 = f4_load(&W_l[(d0 + 3) * 128 + e0]);
        a.x += qv.x * w0.x + qv.y * w1.x + qv.z * w2.x + qv.w * w3.x;
        a.y += qv.x * w0.y + qv.y * w1.y + qv.z * w2.y + qv.w * w3.y;
        a.z += qv.x * w0.z + qv.y * w1.z + qv.z * w2.z + qv.w * w3.z;
        a.w += qv.x * w0.w + qv.y * w1.w + qv.z * w2.w + qv.w * w3.w;
      }
      f4_store(&qk2_ws[(((size_t)b * Nn + n) * Hh + h) * Ee + e0], a);
    }
  }
  __syncthreads();
  {  // qb2: thread -> (n, h)
    const int nn = t >> 2, h2 = t & 3;
    float s = 0.f;
    for (int d = 0; d < 32; ++d)
      s += q_l[nn * 132 + h2 * 32 + d] * bk_l[h2 * 32 + d];
    qb2_ws[((size_t)b * Nn + nn) * Hh + h2] = s;
  }
}

// ---------------- kt/vt projection: block = (b, s) -------------------------
// x[b][s][:][:] is 64x128 contiguous -> staged once. W staged in 16-k chunks
// (8x/block) -> LDS 50.6 KB -> 3 blocks/CU (was 67.5 KB -> 2).
// Thread (ng=t>>4, tx=t&15): 4 n-rows x (2+2) f4 cols.
__global__ __launch_bounds__(256, 3) void ktvt_kernel(
    const float* __restrict__ x,
    const float* __restrict__ tWk, const float* __restrict__ tbk,
    const float* __restrict__ tWv, const float* __restrict__ tbv,
    float* __restrict__ kt_ws, float* __restrict__ vt_ws) {
  __shared__ float x_l[64 * 132];    // [n][132]
  __shared__ float Wk_l[16 * 132];   // 16-k chunk transposed [k][e]
  __shared__ float Wv_l[16 * 132];
  const int b = blockIdx.x;
  const int s = blockIdx.y;
  const int t = threadIdx.x;
  const int ng = t >> 4;        // 0..15 -> 4 n rows each
  const int tx = t & 15;        // cols tx*4 and 64+tx*4
  const size_t xbase = (((size_t)b * Ss + s) * Nn) * Ee;
  for (int idx = t; idx < 2048; idx += 256) {
    int nn = idx >> 5, e4 = (idx & 31) << 2;
    f4_store(&x_l[nn * 132 + e4], f4_load(&x[xbase + nn * Ee + e4]));
  }
  float4 aK[4][2], aV[4][2];
#pragma unroll
  for (int j = 0; j < 4; ++j)
#pragma unroll
    for (int c = 0; c < 2; ++c) {
      aK[j][c] = make_float4(0.f, 0.f, 0.f, 0.f);
      aV[j][c] = make_float4(0.f, 0.f, 0.f, 0.f);
    }
  for (int kc = 0; kc < 8; ++kc) {
    __syncthreads();  // x ready (kc=0) / prev compute done with W tiles
    // stage 16k x 128e of each W, transposed: 512 f4 per mat, 1024 total
    for (int idx = t; idx < 1024; idx += 256) {
      int which = idx >> 9, i2 = idx & 511;
      int e = i2 & 127, k0 = (i2 >> 7) << 2;
      const float* Wg = which ? tWv : tWk;
      float* Wl = which ? Wv_l : Wk_l;
      float4 w = f4_load(&Wg[e * Ee + kc * 16 + k0]);
      Wl[(k0 + 0) * 132 + e] = w.x;
      Wl[(k0 + 1) * 132 + e] = w.y;
      Wl[(k0 + 2) * 132 + e] = w.z;
      Wl[(k0 + 3) * 132 + e] = w.w;
    }
    __syncthreads();
#pragma unroll
    for (int k = 0; k < 16; ++k) {
      float xv[4];
#pragma unroll
      for (int j = 0; j < 4; ++j)
        xv[j] = x_l[(ng * 4 + j) * 132 + kc * 16 + k];
      float4 wk0 = f4_load(&Wk_l[k * 132 + tx * 4]);
      float4 wk1 = f4_load(&Wk_l[k * 132 + 64 + tx * 4]);
      float4 wv0 = f4_load(&Wv_l[k * 132 + tx * 4]);
      float4 wv1 = f4_load(&Wv_l[k * 132 + 64 + tx * 4]);
#pragma unroll
      for (int j = 0; j < 4; ++j) {
        float a = xv[j];
        aK[j][0].x += a * wk0.x; aK[j][0].y += a * wk0.y;
        aK[j][0].z += a * wk0.z; aK[j][0].w += a * wk0.w;
        aK[j][1].x += a * wk1.x; aK[j][1].y += a * wk1.y;
        aK[j][1].z += a * wk1.z; aK[j][1].w += a * wk1.w;
        aV[j][0].x += a * wv0.x; aV[j][0].y += a * wv0.y;
        aV[j][0].z += a * wv0.z; aV[j][0].w += a * wv0.w;
        aV[j][1].x += a * wv1.x; aV[j][1].y += a * wv1.y;
        aV[j][1].z += a * wv1.z; aV[j][1].w += a * wv1.w;
      }
    }
  }
  float4 bk0 = f4_load(&tbk[tx * 4]);
  float4 bk1 = f4_load(&tbk[64 + tx * 4]);
  float4 bv0 = f4_load(&tbv[tx * 4]);
  float4 bv1 = f4_load(&tbv[64 + tx * 4]);
#pragma unroll
  for (int j = 0; j < 4; ++j) {
    const int n = ng * 4 + j;
    const size_t obase = (((size_t)b * Nn + n) * Ss + s) * Ee;
    float4 o;
    o.x = aK[j][0].x + bk0.x; o.y = aK[j][0].y + bk0.y;
    o.z = aK[j][0].z + bk0.z; o.w = aK[j][0].w + bk0.w;
    f4_store(&kt_ws[obase + tx * 4], o);
    o.x = aK[j][1].x + bk1.x; o.y = aK[j][1].y + bk1.y;
    o.z = aK[j][1].z + bk1.z; o.w = aK[j][1].w + bk1.w;
    f4_store(&kt_ws[obase + 64 + tx * 4], o);
    o.x = aV[j][0].x + bv0.x; o.y = aV[j][0].y + bv0.y;
    o.z = aV[j][0].z + bv0.z; o.w = aV[j][0].w + bv0.w;
    f4_store(&vt_ws[obase + tx * 4], o);
    o.x = aV[j][1].x + bv1.x; o.y = aV[j][1].y + bv1.y;
    o.z = aV[j][1].z + bv1.z; o.w = aV[j][1].w + bv1.w;
    f4_store(&vt_ws[obase + 64 + tx * 4], o);
  }
}

// ---------------- main fused kernel ----------------------------------------
// grid dim3(64, 16): bx = b, by = chunk (ms = by>>3, nc = by&7).
// Linear id = bx + by*64 -> id%8 = b%8: all 16 blocks of one b share an XCD
// -> kt/vt[b] (4 MB) stays L2-resident.
// 512 thr = 8 waves; wave w owns n = n0 + w -> adjacency skip is
// wave-uniform (exact: masked (n,m) is an online-update no-op).
__global__ __launch_bounds__(512, 6) void main_kernel(
    const float* __restrict__ kt_ws, const float* __restrict__ vt_ws,
    const float* __restrict__ qt_ws, const float* __restrict__ qk2_ws,
    const float* __restrict__ qb2_ws, const int* __restrict__ adj,
    float* __restrict__ pctxw, float* __restrict__ pM,
    float* __restrict__ pL) {
  __shared__ float kvK[32 * 132];      // kt tile, stride 132
  __shared__ float kvV[32 * 132];      // vt tile
  __shared__ float p_l[32 * 36];       // (w*4+h)*36 + s
  __shared__ float qt_l[8 * 128];
  __shared__ int adj_l[8 * 64];
  const int b = blockIdx.x;
  const int chunk = blockIdx.y;
  const int ms = chunk >> 3;
  const int n0 = (chunk & 7) * 8;
  const int m0 = ms * 32;
  const int t = threadIdx.x;
  const int w = t >> 6;        // wave index = local n
  const int l64 = t & 63;
  const int gn = n0 + w;
  // scores mapping: lane -> (s, h-pair)
  const int sc_s = l64 & 31;
  const int sc_h0 = (l64 >> 5) * 2;   // rows h0, h0+1
  // PV mapping: lane -> (s-half, e-f4)
  const int sh = l64 >> 5;
  const int eidx = l64 & 31;
  const int e4 = eidx << 2;
  const int ph = eidx >> 3;           // head owning this e-range

  for (int idx = t; idx < 256; idx += 512)  // qt rows n0..n0+7 (f4)
    f4_store(&qt_l[idx * 4],
             f4_load(&qt_ws[((size_t)b * Nn + n0 + (idx >> 5)) * Ee +
                            ((idx & 31) << 2)]));
  if (t < 512) adj_l[t] = adj[(n0 + (t >> 6)) * Nn + (t & 63)];

  // m-invariant per-thread state
  float4 qk2r[4];
  float qb2r[4];
#pragma unroll
  for (int h = 0; h < 4; ++h) {
    qk2r[h] = f4_load(&qk2_ws[(((size_t)b * Nn + gn) * Hh + h) * Ee + e4]);
    qb2r[h] = qb2_ws[((size_t)b * Nn + gn) * Hh + h];
  }
  float4 cw[4];
  float Mh[4], Lh[4];
#pragma unroll
  for (int h = 0; h < 4; ++h) {
    cw[h] = make_float4(0.f, 0.f, 0.f, 0.f);
    Mh[h] = -1e30f;
    Lh[h] = 0.f;
  }
  __syncthreads();

  for (int mi = 0; mi < 32; ++mi) {
    const int m = m0 + mi;
    const size_t kvbase = ((size_t)b * Nn + m) * Ss * Ee;
    // ---- stage kt AND vt (all threads) ----
#pragma unroll
    for (int p = 0; p < 2; ++p) {
      int idx = p * 512 + t;
      int s = idx >> 5, e = (idx & 31) << 2;
      f4_store(&kvK[s * 132 + e], f4_load(&kt_ws[kvbase + s * Ee + e]));
    }
#pragma unroll
    for (int p = 0; p < 2; ++p) {
      int idx = p * 512 + t;
      int s = idx >> 5, e = (idx & 31) << 2;
      f4_store(&kvV[s * 132 + e], f4_load(&vt_ws[kvbase + s * Ee + e]));
    }
    __syncthreads();
    const int am = adj_l[w * 64 + m];  // wave-uniform
    if (am) {
      // ---- scores + softmax for rows (sc_h0, sc_h0+1) ----
#pragma unroll
      for (int j = 0; j < 2; ++j) {
        const int h = sc_h0 + j;
        float a = 0.f;
#pragma unroll
        for (int d0 = 0; d0 < 32; d0 += 4)
          a += dot4(f4_load(&qt_l[w * 128 + h * 32 + d0]),
                    f4_load(&kvK[sc_s * 132 + h * 32 + d0]));
        a *= SCALE;
        float mx = a;
#pragma unroll
        for (int msk = 1; msk < 32; msk <<= 1)
          mx = fmaxf(mx, __shfl_xor(mx, msk));
        float ww = __expf(a - mx);
        float sum = ww;
#pragma unroll
        for (int msk = 1; msk < 32; msk <<= 1) sum += __shfl_xor(sum, msk);
        p_l[(w * 4 + h) * 36 + sc_s] = ww * (1.0f / sum);
      }
    }
    __syncthreads();  // p ready (and kvK reads done)
    if (am) {
      // ---- PV: partial over this lane's s-half, then combine ----
      float4 c1 = make_float4(0.f, 0.f, 0.f, 0.f);
      const float* prow = &p_l[(w * 4 + ph) * 36 + sh * 16];
#pragma unroll
      for (int s4 = 0; s4 < 4; ++s4) {
        float4 pw = f4_load(&prow[s4 * 4]);
        const int sb = sh * 16 + s4 * 4;
        float4 v0 = f4_load(&kvV[(sb + 0) * 132 + e4]);
        float4 v1 = f4_load(&kvV[(sb + 1) * 132 + e4]);
        float4 v2 = f4_load(&kvV[(sb + 2) * 132 + e4]);
        float4 v3 = f4_load(&kvV[(sb + 3) * 132 + e4]);
        c1.x += pw.x * v0.x + pw.y * v1.x + pw.z * v2.x + pw.w * v3.x;
        c1.y += pw.x * v0.y + pw.y * v1.y + pw.z * v2.y + pw.w * v3.y;
        c1.z += pw.x * v0.z + pw.y * v1.z + pw.z * v2.z + pw.w * v3.z;
        c1.w += pw.x * v0.w + pw.y * v1.w + pw.z * v2.w + pw.w * v3.w;
      }
      c1.x += __shfl_xor(c1.x, 32);
      c1.y += __shfl_xor(c1.y, 32);
      c1.z += __shfl_xor(c1.z, 32);
      c1.w += __shfl_xor(c1.w, 32);
      // ---- sc2: full e-contraction per head (32-lane butterfly) ----
      float s2[4];
#pragma unroll
      for (int h2 = 0; h2 < 4; ++h2) {
        float part = dot4(qk2r[h2], c1);
#pragma unroll
        for (int msk = 1; msk < 32; msk <<= 1) part += __shfl_xor(part, msk);
        s2[h2] = (part + qb2r[h2]) * SCALE;
      }
      // ---- online update (identical across lanes/halves) ----
#pragma unroll
      for (int h2 = 0; h2 < 4; ++h2) {
        float mnew = fmaxf(Mh[h2], s2[h2]);
        float r = __expf(Mh[h2] - mnew);
        float ww = __expf(s2[h2] - mnew);
        Lh[h2] = Lh[h2] * r + ww;
        cw[h2].x = cw[h2].x * r + ww * c1.x;
        cw[h2].y = cw[h2].y * r + ww * c1.y;
        cw[h2].z = cw[h2].z * r + ww * c1.z;
        cw[h2].w = cw[h2].w * r + ww * c1.w;
        Mh[h2] = mnew;
      }
    }
    __syncthreads();  // done reading kv/p before next stage
  }
  // ---- write partials (half 0 holds full copy) ----
  const size_t pidx = ((size_t)(ms * Bb + b) * Nn + gn);
  if (l64 < 32) {
#pragma unroll
    for (int h2 = 0; h2 < 4; ++h2)
      f4_store(&pctxw[(pidx * 4 + h2) * Ee + e4], cw[h2]);
    if (l64 == 0) {
#pragma unroll
      for (int h2 = 0; h2 < 4; ++h2) {
        pM[pidx * 4 + h2] = Mh[h2];
        pL[pidx * 4 + h2] = Lh[h2];
      }
    }
  }
}

// ---------------- reducer: combine partials, apply Wv', sWo ----------------
// grid (64 b, 8 nc)
__global__ __launch_bounds__(256) void reduce_kernel(
    const float* __restrict__ pctxw, const float* __restrict__ pM,
    const float* __restrict__ pL, const float* __restrict__ Wvp,
    const float* __restrict__ bvp, const float* __restrict__ sWo,
    const float* __restrict__ sbo, float* __restrict__ out) {
  __shared__ float cwf[8 * 4 * 132];
  __shared__ float c2l[8 * 132];
  const int b = blockIdx.x;
  const int n0 = blockIdx.y * 8;
  const int t = threadIdx.x;
  const int n = t >> 5;
  const int lane = t & 31;
  const int e4 = lane << 2;
  const int gn = n0 + n;
#pragma unroll
  for (int h = 0; h < 4; ++h) {
    const size_t i0 = ((size_t)(0 * Bb + b) * Nn + gn) * 4 + h;
    const size_t i1 = ((size_t)(1 * Bb + b) * Nn + gn) * 4 + h;
    float M0 = pM[i0], M1 = pM[i1];
    float L0 = pL[i0], L1 = pL[i1];
    float Msx = fmaxf(M0, M1);
    float r0 = __expf(M0 - Msx), r1 = __expf(M1 - Msx);
    float inv = 1.0f / (r0 * L0 + r1 * L1);
    float4 c0 = f4_load(&pctxw[i0 * Ee + e4]);
    float4 c1 = f4_load(&pctxw[i1 * Ee + e4]);
    float4 res;
    res.x = (r0 * c0.x + r1 * c1.x) * inv;
    res.y = (r0 * c0.y + r1 * c1.y) * inv;
    res.z = (r0 * c0.z + r1 * c1.z) * inv;
    res.w = (r0 * c0.w + r1 * c1.w) * inv;
    f4_store(&cwf[(n * 4 + h) * 132 + e4], res);
  }
  __syncthreads();
  // ctx2[n][k4..k4+3] = bv'[k] + sum_e Wv'[k][e]*cwf[n][h(k)][e]
  {
    const int k4 = lane << 2;
    const int h = lane >> 3;
    float4 a = f4_load(&bvp[k4]);
    for (int ee = 0; ee < 128; ee += 4) {
      float4 cv = f4_load(&cwf[(n * 4 + h) * 132 + ee]);
      float4 w0 = f4_load(&Wvp[(k4 + 0) * Ee + ee]);
      float4 w1 = f4_load(&Wvp[(k4 + 1) * Ee + ee]);
      float4 w2 = f4_load(&Wvp[(k4 + 2) * Ee + ee]);
      float4 w3 = f4_load(&Wvp[(k4 + 3) * Ee + ee]);
      a.x += dot4(w0, cv);
      a.y += dot4(w1, cv);
      a.z += dot4(w2, cv);
      a.w += dot4(w3, cv);
    }
    f4_store(&c2l[n * 132 + k4], a);
  }
  __syncthreads();
  // out[b][gn][e4..] = sbo + sWo @ ctx2
  {
    float4 o = f4_load(&sbo[e4]);
    for (int k0 = 0; k0 < 128; k0 += 4) {
      float4 cv = f4_load(&c2l[n * 132 + k0]);
      float4 w0 = f4_load(&sWo[(e4 + 0) * Ee + k0]);
      float4 w1 = f4_load(&sWo[(e4 + 1) * Ee + k0]);
      float4 w2 = f4_load(&sWo[(e4 + 2) * Ee + k0]);
      float4 w3 = f4_load(&sWo[(e4 + 3) * Ee + k0]);
      o.x += dot4(w0, cv);
      o.y += dot4(w1, cv);
      o.z += dot4(w2, cv);
      o.w += dot4(w3, cv);
    }
    f4_store(&out[((size_t)b * Nn + gn) * Ee + e4], o);
  }
}

// ---------------------------------------------------------------------------
extern "C" void kernel_launch(void* const* d_in, const int* in_sizes, int n_in,
                              void* d_out, int out_size, void* d_ws,
                              size_t ws_size, hipStream_t stream) {
  const float* x = (const float*)d_in[0];
  const int* adj = (const int*)d_in[1];
  const float* tWq = (const float*)d_in[2];
  const float* tbq = (const float*)d_in[3];
  const float* tWk = (const float*)d_in[4];
  const float* tbk = (const float*)d_in[5];
  const float* tWv = (const float*)d_in[6];
  const float* tbv = (const float*)d_in[7];
  const float* tWo = (const float*)d_in[8];
  const float* tbo = (const float*)d_in[9];
  const float* sWq = (const float*)d_in[10];
  const float* sbq = (const float*)d_in[11];
  const float* sWk = (const float*)d_in[12];
  const float* sbk = (const float*)d_in[13];
  const float* sWv = (const float*)d_in[14];
  const float* sbv = (const float*)d_in[15];
  const float* sWo = (const float*)d_in[16];
  const float* sbo = (const float*)d_in[17];
  float* out = (float*)d_out;

  float* ws = (float*)d_ws;
  const size_t ktvt_elems = (size_t)Bb * Nn * Ss * Ee;  // 16,777,216
  float* kt_ws = ws;
  float* vt_ws = kt_ws + ktvt_elems;
  float* qt_ws = vt_ws + ktvt_elems;                       // 524,288
  float* qk2_ws = qt_ws + (size_t)Bb * Nn * Ee;            // 2,097,152
  float* qb2_ws = qk2_ws + (size_t)Bb * Nn * Hh * Ee;      // 16,384
  float* Wkp = qb2_ws + (size_t)Bb * Nn * Hh;
  float* Wvp = Wkp + Ee * Ee;
  float* bkp = Wvp + Ee * Ee;
  float* bvp = bkp + Ee;
  float* pctxw = bvp + Ee;                                 // MS*B*N*4*128
  float* pM = pctxw + (size_t)MS * Bb * Nn * 4 * Ee;       // MS*B*N*4
  float* pL = pM + (size_t)MS * Bb * Nn * 4;

  fuse_weights_kernel<<<dim3(Ee, 2), 128, 0, stream>>>(
      sWk, sbk, sWv, sbv, tWo, tbo, Wkp, bkp, Wvp, bvp);
  qproj_kernel<<<dim3(Bb, 2), 256, 0, stream>>>(
      x, tWq, tbq, sWq, sbq, Wkp, bkp, qt_ws, qk2_ws, qb2_ws);
  ktvt_kernel<<<dim3(Bb, Ss), 256, 0, stream>>>(x, tWk, tbk, tWv, tbv, kt_ws,
                                                vt_ws);
  main_kernel<<<dim3(Bb, 16), 512, 0, stream>>>(
      kt_ws, vt_ws, qt_ws, qk2_ws, qb2_ws, adj, pctxw, pM, pL);
  reduce_kernel<<<dim3(Bb, 8), 256, 0, stream>>>(pctxw, pM, pL, Wvp, bvp, sWo,
                                                 sbo, out);
}